// Round 23
// baseline (308.082 us; speedup 1.0000x reference)
//
#include <hip/hip_runtime.h>

#define ND 128   // node feature dim D
#define ED 32    // edge radial basis dim
#define LN_EPS 1e-5f

typedef __attribute__((ext_vector_type(8))) short bf16x8;
typedef __attribute__((ext_vector_type(4))) float f32x4;

__device__ __forceinline__ unsigned short f32_to_bf16(float f) {
    const unsigned u = __float_as_uint(f);
    return (unsigned short)((u + 0x7FFFu + ((u >> 16) & 1u)) >> 16);
}
__device__ __forceinline__ float bf16f(unsigned short h) {
    return __uint_as_float(((unsigned)h) << 16);
}

// ---------------------------------------------------------------------------
// Histogram of center indices (int64/int32 autodetect).
// ---------------------------------------------------------------------------
__global__ void conv_hist_kernel(const unsigned* __restrict__ raw,
                                 int* __restrict__ cnt, int E) {
    __shared__ int s_is64;
    if (threadIdx.x == 0) {
        unsigned acc = 0;
        for (int i = 1; i < 512; i += 2) acc |= raw[i];
        s_is64 = (acc == 0) ? 1 : 0;
    }
    __syncthreads();
    const int is64 = s_is64;
    const int tid = blockIdx.x * blockDim.x + threadIdx.x;
    const int stride = gridDim.x * blockDim.x;
    if (is64) {
        for (int e = tid; e < E; e += stride)
            atomicAdd(&cnt[(int)raw[(size_t)2 * e]], 1);
    } else {
        for (int e = tid; e < E; e += stride)
            atomicAdd(&cnt[(int)raw[e]], 1);
    }
}

// ---------------------------------------------------------------------------
// Multi-block dual scan, phase 1: per-block reduce of (cnt, padded cnt).
// ---------------------------------------------------------------------------
__global__ __launch_bounds__(256) void scan1_kernel(
    const int* __restrict__ cnt, int* __restrict__ sum1,
    int* __restrict__ sum2, int N) {
    __shared__ int l1[256], l2[256];
    const int t = threadIdx.x;
    const int i = blockIdx.x * 256 + t;
    const int c = (i < N) ? cnt[i] : 0;
    l1[t] = c;
    l2[t] = (c + 15) & ~15;
    __syncthreads();
    for (int off = 128; off > 0; off >>= 1) {
        if (t < off) { l1[t] += l1[t + off]; l2[t] += l2[t + off]; }
        __syncthreads();
    }
    if (t == 0) { sum1[blockIdx.x] = l1[0]; sum2[blockIdx.x] = l2[0]; }
}

// ---------------------------------------------------------------------------
// Phase 2: single-block scan of block sums -> exclusive block offsets;
// writes base[N] / pbase[N] grand totals.
// ---------------------------------------------------------------------------
__global__ __launch_bounds__(1024) void scan2_kernel(
    int* __restrict__ sum1, int* __restrict__ sum2,
    int* __restrict__ base, int* __restrict__ pbase, int NB, int N) {
    __shared__ int l1[1024], l2[1024];
    const int t = threadIdx.x;
    const int v1 = (t < NB) ? sum1[t] : 0;
    const int v2 = (t < NB) ? sum2[t] : 0;
    l1[t] = v1; l2[t] = v2;
    __syncthreads();
    for (int off = 1; off < 1024; off <<= 1) {
        int a = 0, b = 0;
        if (t >= off) { a = l1[t - off]; b = l2[t - off]; }
        __syncthreads();
        l1[t] += a; l2[t] += b;
        __syncthreads();
    }
    if (t < NB) {
        sum1[t] = l1[t] - v1;
        sum2[t] = l2[t] - v2;
    }
    if (t == NB - 1) { base[N] = l1[t]; pbase[N] = l2[t]; }
}

// ---------------------------------------------------------------------------
// Phase 3: intra-block exclusive scan + block offset -> base/pbase; zero cur.
// ---------------------------------------------------------------------------
__global__ __launch_bounds__(256) void scan3_kernel(
    const int* __restrict__ cnt, const int* __restrict__ sum1,
    const int* __restrict__ sum2, int* __restrict__ base,
    int* __restrict__ pbase, int* __restrict__ cur, int N) {
    __shared__ int l1[256], l2[256];
    const int t = threadIdx.x;
    const int i = blockIdx.x * 256 + t;
    const int c = (i < N) ? cnt[i] : 0;
    const int p = (c + 15) & ~15;
    l1[t] = c; l2[t] = p;
    __syncthreads();
    for (int off = 1; off < 256; off <<= 1) {
        int a = 0, b = 0;
        if (t >= off) { a = l1[t - off]; b = l2[t - off]; }
        __syncthreads();
        l1[t] += a; l2[t] += b;
        __syncthreads();
    }
    if (i < N) {
        base[i]  = sum1[blockIdx.x] + l1[t] - c;
        pbase[i] = sum2[blockIdx.x] + l2[t] - p;
        cur[i] = 0;
    }
}

// ---------------------------------------------------------------------------
// FUSED mid-stage kernel (round-22 proven): padfill ∥ scatter ∥ gemm ∥ wcc
// via blockIdx bands; disjoint write sets; overlaps latency-bound scatter
// with VALU-bound gemm across CUs.
// ---------------------------------------------------------------------------
__global__ __launch_bounds__(512, 4) void fused_mid_kernel(
    const unsigned* __restrict__ raw, const int* __restrict__ cnt,
    const int* __restrict__ pbase, int* __restrict__ cur,
    int2* __restrict__ epad,
    const float* __restrict__ A, const float* __restrict__ W,
    float* __restrict__ P,
    const float* __restrict__ Wc, const float* __restrict__ Wcat,
    float* __restrict__ wcc,
    int N, int E, int NPF, int NSC, int NG) {
    const int bid = blockIdx.x;
    if (bid < NPF) {
        const int v = bid * 512 + (int)threadIdx.x;
        if (v < N) {
            const int s = pbase[v] + cnt[v];
            const int t = pbase[v + 1];
            for (int p = s; p < t; ++p) epad[p] = make_int2(0, 0);
        }
        if (bid == 0 && threadIdx.x < 64) {
            const int tail = pbase[N];
            epad[tail + threadIdx.x] = make_int2(0, 0);
        }
        return;
    }
    if (bid < NPF + NSC) {
        __shared__ int s_is64;
        if (threadIdx.x == 0) {
            unsigned acc = 0;
            for (int i = 1; i < 512; i += 2) acc |= raw[i];
            s_is64 = (acc == 0) ? 1 : 0;
        }
        __syncthreads();
        const int is64 = s_is64;
        const int tid = (bid - NPF) * 512 + (int)threadIdx.x;
        const int stride = NSC * 512;
        if (is64) {
            for (int e = tid; e < E; e += stride) {
                const int c = (int)raw[(size_t)2 * e];
                const int n = (int)raw[(size_t)2 * E + (size_t)2 * e];
                const int pos = pbase[c] + atomicAdd(&cur[c], 1);
                epad[pos] = make_int2(e, n);
            }
        } else {
            for (int e = tid; e < E; e += stride) {
                const int c = (int)raw[e];
                const int n = (int)raw[(size_t)E + e];
                const int pos = pbase[c] + atomicAdd(&cur[c], 1);
                epad[pos] = make_int2(e, n);
            }
        }
        return;
    }
    if (bid < NPF + NSC + NG) {
        __shared__ float Ws[ND * ND];
        {
            float4* d = (float4*)Ws;
            const float4* s = (const float4*)W;
            for (int i = threadIdx.x; i < (ND * ND) / 4; i += 512) d[i] = s[i];
        }
        __syncthreads();
        const int bg = bid - NPF - NSC;
        const int slot = (int)(threadIdx.x >> 5);
        const int j0 = ((int)threadIdx.x & 31) * 4;
        const int rbase = bg * 64 + slot * 4;
        const int r0 = (rbase + 0 < N) ? rbase + 0 : N - 1;
        const int r1 = (rbase + 1 < N) ? rbase + 1 : N - 1;
        const int r2 = (rbase + 2 < N) ? rbase + 2 : N - 1;
        const int r3 = (rbase + 3 < N) ? rbase + 3 : N - 1;
        const float* ap0 = A + (size_t)r0 * ND;
        const float* ap1 = A + (size_t)r1 * ND;
        const float* ap2 = A + (size_t)r2 * ND;
        const float* ap3 = A + (size_t)r3 * ND;
        float4 acc0 = {0,0,0,0}, acc1 = {0,0,0,0};
        float4 acc2 = {0,0,0,0}, acc3 = {0,0,0,0};
#pragma unroll 2
        for (int c = 0; c < 32; ++c) {
            const float4 a0 = *(const float4*)(ap0 + c * 4);
            const float4 a1 = *(const float4*)(ap1 + c * 4);
            const float4 a2 = *(const float4*)(ap2 + c * 4);
            const float4 a3 = *(const float4*)(ap3 + c * 4);
#pragma unroll
            for (int kk = 0; kk < 4; ++kk) {
                const float4 w = *(const float4*)&Ws[(c * 4 + kk) * ND + j0];
                const float x0 = ((const float*)&a0)[kk];
                const float x1 = ((const float*)&a1)[kk];
                const float x2 = ((const float*)&a2)[kk];
                const float x3 = ((const float*)&a3)[kk];
                acc0.x += x0 * w.x; acc0.y += x0 * w.y;
                acc0.z += x0 * w.z; acc0.w += x0 * w.w;
                acc1.x += x1 * w.x; acc1.y += x1 * w.y;
                acc1.z += x1 * w.z; acc1.w += x1 * w.w;
                acc2.x += x2 * w.x; acc2.y += x2 * w.y;
                acc2.z += x2 * w.z; acc2.w += x2 * w.w;
                acc3.x += x3 * w.x; acc3.y += x3 * w.y;
                acc3.z += x3 * w.z; acc3.w += x3 * w.w;
            }
        }
        if (rbase + 0 < N) *(float4*)&P[(size_t)r0 * ND + j0] = acc0;
        if (rbase + 1 < N) *(float4*)&P[(size_t)r1 * ND + j0] = acc1;
        if (rbase + 2 < N) *(float4*)&P[(size_t)r2 * ND + j0] = acc2;
        if (rbase + 3 < N) *(float4*)&P[(size_t)r3 * ND + j0] = acc3;
        return;
    }
    {
        const int bw = bid - NPF - NSC - NG;
        const int i = bw * 4 + ((int)threadIdx.x >> 7);
        const int j = (int)threadIdx.x & 127;
        float acc = 0.f;
        for (int k = 0; k < ND; ++k)
            acc += Wc[i * ND + k] * Wcat[k * ND + j];
        wcc[i * ND + j] = acc;
    }
}

// ---------------------------------------------------------------------------
// MFMA segmented edge reduction v4: 2-term split-bf16. Dropping the B-residual
// (bl[8] = 32 VGPRs) frees registers for occupancy: D = ah@bh + al@bh keeps
// A exact (hi+lo reconstructs fp32); only W is bf16-quantized (~0.002 rel),
// which LN rescaling shrinks to ~0.002-0.01 absolute on the output.
// __launch_bounds__(256,5) caps VGPR at 102 -> 5 waves/SIMD (was 112 -> 4).
// Grid 1280 blocks = 5120 waves resident in one pass, cpw 10.
// ---------------------------------------------------------------------------
__global__ __launch_bounds__(256, 5) void seg_mfma_kernel(
    const int* __restrict__ base, const int* __restrict__ pbase,
    const int2* __restrict__ epad, const float* __restrict__ edge_attr,
    const float* __restrict__ W_edge, const float* __restrict__ P,
    float* __restrict__ m, int N, int CPW) {
    const int l   = (int)threadIdx.x & 63;
    const int r16 = l & 15;
    const int kg  = l >> 4;
    bf16x8 bh[8];
#pragma unroll
    for (int t = 0; t < 8; ++t) {
#pragma unroll
        for (int j = 0; j < 8; ++j) {
            const float wv = W_edge[(kg * 8 + j) * ND + t * 16 + r16];
            bh[t][j] = (short)f32_to_bf16(wv);
        }
    }
    const f32x4 zero = {0.f, 0.f, 0.f, 0.f};
    const int wid = blockIdx.x * 4 + ((int)threadIdx.x >> 6);
    const int v0 = wid * CPW;
    if (v0 >= N) return;
    const int v1 = min(v0 + CPW, N);

    int pos = pbase[v0];
    int2 epA = epad[pos + r16];
    int2 epB = epad[pos + 16 + r16];
    float4 xA, yA, xB, yB;
    {
        const float* ap = edge_attr + (size_t)epA.x * ED + kg * 8;
        xA = *(const float4*)ap; yA = *(const float4*)(ap + 4);
        const float* bp = edge_attr + (size_t)epB.x * ED + kg * 8;
        xB = *(const float4*)bp; yB = *(const float4*)(bp + 4);
    }

    for (int v = v0; v < v1; ++v) {
        const int vend = pbase[v] + (base[v + 1] - base[v]);
        const int pend = pbase[v + 1];
        float part[8] = {0.f, 0.f, 0.f, 0.f, 0.f, 0.f, 0.f, 0.f};
        while (pos < pend) {
            const int2 epC = epad[pos + 32 + r16];
            float4 x = xA, y = yA;
            if (pos + r16 >= vend) {
                x.x = x.y = x.z = x.w = 0.f;
                y = x;
            }
            bf16x8 ah, al;
#pragma unroll
            for (int j = 0; j < 4; ++j) {
                const float fx = ((const float*)&x)[j];
                const unsigned short hx = f32_to_bf16(fx);
                ah[j] = (short)hx;
                al[j] = (short)f32_to_bf16(fx - bf16f(hx));
                const float fy = ((const float*)&y)[j];
                const unsigned short hy = f32_to_bf16(fy);
                ah[4 + j] = (short)hy;
                al[4 + j] = (short)f32_to_bf16(fy - bf16f(hy));
            }
            const int n0 = __shfl(epA.y, kg * 4 + 0, 16);
            const int n1 = __shfl(epA.y, kg * 4 + 1, 16);
            const int n2 = __shfl(epA.y, kg * 4 + 2, 16);
            const int n3 = __shfl(epA.y, kg * 4 + 3, 16);
            const float* q0 = P + (size_t)n0 * ND + r16;
            const float* q1 = P + (size_t)n1 * ND + r16;
            const float* q2 = P + (size_t)n2 * ND + r16;
            const float* q3 = P + (size_t)n3 * ND + r16;
#pragma unroll
            for (int t = 0; t < 8; ++t) {
                f32x4 D = __builtin_amdgcn_mfma_f32_16x16x32_bf16(
                    ah, bh[t], zero, 0, 0, 0);
                D = __builtin_amdgcn_mfma_f32_16x16x32_bf16(
                    al, bh[t], D, 0, 0, 0);
                part[t] += D[0] * q0[t * 16];
                part[t] += D[1] * q1[t * 16];
                part[t] += D[2] * q2[t * 16];
                part[t] += D[3] * q3[t * 16];
            }
            epA = epB; xA = xB; yA = yB;
            epB = epC;
            const float* np = edge_attr + (size_t)epB.x * ED + kg * 8;
            xB = *(const float4*)np;
            yB = *(const float4*)(np + 4);
            pos += 16;
        }
#pragma unroll
        for (int t = 0; t < 8; ++t) {
            part[t] += __shfl_xor(part[t], 16);
            part[t] += __shfl_xor(part[t], 32);
        }
        if (l < 16) {
#pragma unroll
            for (int t = 0; t < 8; ++t)
                m[(size_t)v * ND + t * 16 + l] = part[t];
        }
    }
}

// ---------------------------------------------------------------------------
// Fused final: out[r] = LN(node_attr[r]@wcc + m[r]@W_bot). (proven)
// ---------------------------------------------------------------------------
__global__ __launch_bounds__(512, 4) void final_kernel(
    const float* __restrict__ A1, const float* __restrict__ A2,
    const float* __restrict__ W1, const float* __restrict__ W2,
    const float* __restrict__ lnw, const float* __restrict__ lnb,
    float* __restrict__ out, int N) {
    __shared__ float Ws[ND * ND];
    const int slot = (int)(threadIdx.x >> 5);
    const int j0 = ((int)threadIdx.x & 31) * 4;
    const int rbase = blockIdx.x * 64 + slot * 4;
    const int r0 = (rbase + 0 < N) ? rbase + 0 : N - 1;
    const int r1 = (rbase + 1 < N) ? rbase + 1 : N - 1;
    const int r2 = (rbase + 2 < N) ? rbase + 2 : N - 1;
    const int r3 = (rbase + 3 < N) ? rbase + 3 : N - 1;
    float4 acc0 = {0,0,0,0}, acc1 = {0,0,0,0};
    float4 acc2 = {0,0,0,0}, acc3 = {0,0,0,0};

#define K_PHASE(AP, WP)                                                       \
    {                                                                         \
        {                                                                     \
            float4* d = (float4*)Ws;                                          \
            const float4* sw = (const float4*)(WP);                           \
            for (int i = threadIdx.x; i < (ND * ND) / 4; i += 512)            \
                d[i] = sw[i];                                                 \
        }                                                                     \
        __syncthreads();                                                      \
        const float* ap0 = (AP) + (size_t)r0 * ND;                            \
        const float* ap1 = (AP) + (size_t)r1 * ND;                            \
        const float* ap2 = (AP) + (size_t)r2 * ND;                            \
        const float* ap3 = (AP) + (size_t)r3 * ND;                            \
        _Pragma("unroll 2")                                                   \
        for (int c = 0; c < 32; ++c) {                                        \
            const float4 a0 = *(const float4*)(ap0 + c * 4);                  \
            const float4 a1 = *(const float4*)(ap1 + c * 4);                  \
            const float4 a2 = *(const float4*)(ap2 + c * 4);                  \
            const float4 a3 = *(const float4*)(ap3 + c * 4);                  \
            _Pragma("unroll")                                                 \
            for (int kk = 0; kk < 4; ++kk) {                                  \
                const float4 w = *(const float4*)&Ws[(c * 4 + kk) * ND + j0]; \
                const float x0 = ((const float*)&a0)[kk];                     \
                const float x1 = ((const float*)&a1)[kk];                     \
                const float x2 = ((const float*)&a2)[kk];                     \
                const float x3 = ((const float*)&a3)[kk];                     \
                acc0.x += x0 * w.x; acc0.y += x0 * w.y;                       \
                acc0.z += x0 * w.z; acc0.w += x0 * w.w;                       \
                acc1.x += x1 * w.x; acc1.y += x1 * w.y;                       \
                acc1.z += x1 * w.z; acc1.w += x1 * w.w;                       \
                acc2.x += x2 * w.x; acc2.y += x2 * w.y;                       \
                acc2.z += x2 * w.z; acc2.w += x2 * w.w;                       \
                acc3.x += x3 * w.x; acc3.y += x3 * w.y;                       \
                acc3.z += x3 * w.z; acc3.w += x3 * w.w;                       \
            }                                                                 \
        }                                                                     \
        __syncthreads();                                                      \
    }

    K_PHASE(A1, W1)
    K_PHASE(A2, W2)
#undef K_PHASE

    const float4 w4 = *(const float4*)&lnw[j0];
    const float4 b4 = *(const float4*)&lnb[j0];
#define LN_ROW(ACC, RQ, VALID)                                               \
    {                                                                        \
        float4 h = ACC;                                                      \
        float sum = h.x + h.y + h.z + h.w;                                   \
        sum += __shfl_xor(sum, 16); sum += __shfl_xor(sum, 8);               \
        sum += __shfl_xor(sum, 4);  sum += __shfl_xor(sum, 2);               \
        sum += __shfl_xor(sum, 1);                                           \
        const float mean = sum * (1.f / ND);                                 \
        const float4 dd = {h.x - mean, h.y - mean, h.z - mean, h.w - mean};  \
        float qv = dd.x * dd.x + dd.y * dd.y + dd.z * dd.z + dd.w * dd.w;    \
        qv += __shfl_xor(qv, 16); qv += __shfl_xor(qv, 8);                   \
        qv += __shfl_xor(qv, 4);  qv += __shfl_xor(qv, 2);                   \
        qv += __shfl_xor(qv, 1);                                             \
        const float rstd = rsqrtf(qv * (1.f / ND) + LN_EPS);                 \
        if (VALID) {                                                         \
            float4 o;                                                        \
            o.x = dd.x * rstd * w4.x + b4.x;                                 \
            o.y = dd.y * rstd * w4.y + b4.y;                                 \
            o.z = dd.z * rstd * w4.z + b4.z;                                 \
            o.w = dd.w * rstd * w4.w + b4.w;                                 \
            *(float4*)&out[(size_t)(RQ) * ND + j0] = o;                      \
        }                                                                    \
    }
    LN_ROW(acc0, r0, rbase + 0 < N)
    LN_ROW(acc1, r1, rbase + 1 < N)
    LN_ROW(acc2, r2, rbase + 2 < N)
    LN_ROW(acc3, r3, rbase + 3 < N)
#undef LN_ROW
}

// ---------------------------------------------------------------------------
extern "C" void kernel_launch(void* const* d_in, const int* in_sizes, int n_in,
                              void* d_out, int out_size, void* d_ws, size_t ws_size,
                              hipStream_t stream) {
    const float*    node_attr = (const float*)d_in[0];
    const float*    edge_attr = (const float*)d_in[1];
    const unsigned* edge_idx  = (const unsigned*)d_in[2];
    const float*    W_node    = (const float*)d_in[3];
    const float*    W_center  = (const float*)d_in[4];
    const float*    W_concat  = (const float*)d_in[5];
    const float*    W_edge    = (const float*)d_in[6];
    const float*    lnw       = (const float*)d_in[7];
    const float*    lnb       = (const float*)d_in[8];
    float* out = (float*)d_out;

    const int N = in_sizes[0] / ND;   // 50000
    const int E = in_sizes[1] / ED;   // 800000
    const int NB = (N + 255) / 256;
    const size_t PADCAP = (size_t)E + 15 * (size_t)N + 64;

    char* ws = (char*)d_ws;
    float* wcc   = (float*)ws;                          // 64 KB
    float* P     = (float*)(ws + 65536);                // [N,128]
    float* m     = P + (size_t)N * ND;                  // [N,128]
    int2*  epad  = (int2*)(m + (size_t)N * ND);         // [PADCAP]
    int*   cnt   = (int*)(epad + PADCAP);               // [N]
    int*   base  = cnt + N;                             // [N+1]
    int*   pbase = base + N + 1;                        // [N+1]
    int*   cur   = pbase + N + 1;                       // [N]
    int*   sum1  = cur + N;                             // [NB]
    int*   sum2  = sum1 + NB;                           // [NB]

    hipMemsetAsync(cnt, 0, (size_t)N * sizeof(int), stream);
    conv_hist_kernel<<<512, 256, 0, stream>>>(edge_idx, cnt, E);
    scan1_kernel<<<NB, 256, 0, stream>>>(cnt, sum1, sum2, N);
    scan2_kernel<<<1, 1024, 0, stream>>>(sum1, sum2, base, pbase, NB, N);
    scan3_kernel<<<NB, 256, 0, stream>>>(cnt, sum1, sum2, base, pbase, cur, N);
    {
        const int NPF = (N + 511) / 512;     // padfill blocks
        const int NSC = 256;                 // scatter blocks
        const int NG  = (N + 63) / 64;       // gemm blocks
        const int NW  = 32;                  // wcc blocks
        fused_mid_kernel<<<NPF + NSC + NG + NW, 512, 0, stream>>>(
            edge_idx, cnt, pbase, cur, epad,
            node_attr, W_node, P,
            W_center, W_concat, wcc,
            N, E, NPF, NSC, NG);
    }
    {
        const int nblocks = 1280;                    // 5 waves/SIMD resident
        const int nwaves = nblocks * 4;              // 5120
        const int cpw = (N + nwaves - 1) / nwaves;   // 10 for N=50000
        seg_mfma_kernel<<<nblocks, 256, 0, stream>>>(base, pbase, epad,
                                                     edge_attr, W_edge, P, m,
                                                     N, cpw);
    }
    final_kernel<<<(N + 63) / 64, 512, 0, stream>>>(node_attr, m, wcc,
                                                    W_concat + ND * ND,
                                                    lnw, lnb, out, N);
}

// Round 24
// 292.938 us; speedup vs baseline: 1.0517x; 1.0517x over previous
//
#include <hip/hip_runtime.h>

#define ND 128   // node feature dim D
#define ED 32    // edge radial basis dim
#define LN_EPS 1e-5f

typedef __attribute__((ext_vector_type(8))) short bf16x8;
typedef __attribute__((ext_vector_type(4))) float f32x4;

__device__ __forceinline__ unsigned short f32_to_bf16(float f) {
    const unsigned u = __float_as_uint(f);
    return (unsigned short)((u + 0x7FFFu + ((u >> 16) & 1u)) >> 16);
}
__device__ __forceinline__ float bf16f(unsigned short h) {
    return __uint_as_float(((unsigned)h) << 16);
}

// ---------------------------------------------------------------------------
// Histogram of center indices (int64/int32 autodetect).
// ---------------------------------------------------------------------------
__global__ void conv_hist_kernel(const unsigned* __restrict__ raw,
                                 int* __restrict__ cnt, int E) {
    __shared__ int s_is64;
    if (threadIdx.x == 0) {
        unsigned acc = 0;
        for (int i = 1; i < 512; i += 2) acc |= raw[i];
        s_is64 = (acc == 0) ? 1 : 0;
    }
    __syncthreads();
    const int is64 = s_is64;
    const int tid = blockIdx.x * blockDim.x + threadIdx.x;
    const int stride = gridDim.x * blockDim.x;
    if (is64) {
        for (int e = tid; e < E; e += stride)
            atomicAdd(&cnt[(int)raw[(size_t)2 * e]], 1);
    } else {
        for (int e = tid; e < E; e += stride)
            atomicAdd(&cnt[(int)raw[e]], 1);
    }
}

// ---------------------------------------------------------------------------
// Multi-block dual scan, phase 1: per-block reduce of (cnt, padded cnt).
// ---------------------------------------------------------------------------
__global__ __launch_bounds__(256) void scan1_kernel(
    const int* __restrict__ cnt, int* __restrict__ sum1,
    int* __restrict__ sum2, int N) {
    __shared__ int l1[256], l2[256];
    const int t = threadIdx.x;
    const int i = blockIdx.x * 256 + t;
    const int c = (i < N) ? cnt[i] : 0;
    l1[t] = c;
    l2[t] = (c + 15) & ~15;
    __syncthreads();
    for (int off = 128; off > 0; off >>= 1) {
        if (t < off) { l1[t] += l1[t + off]; l2[t] += l2[t + off]; }
        __syncthreads();
    }
    if (t == 0) { sum1[blockIdx.x] = l1[0]; sum2[blockIdx.x] = l2[0]; }
}

// ---------------------------------------------------------------------------
// Phase 2: single-block scan of block sums -> exclusive block offsets;
// writes base[N] / pbase[N] grand totals.
// ---------------------------------------------------------------------------
__global__ __launch_bounds__(1024) void scan2_kernel(
    int* __restrict__ sum1, int* __restrict__ sum2,
    int* __restrict__ base, int* __restrict__ pbase, int NB, int N) {
    __shared__ int l1[1024], l2[1024];
    const int t = threadIdx.x;
    const int v1 = (t < NB) ? sum1[t] : 0;
    const int v2 = (t < NB) ? sum2[t] : 0;
    l1[t] = v1; l2[t] = v2;
    __syncthreads();
    for (int off = 1; off < 1024; off <<= 1) {
        int a = 0, b = 0;
        if (t >= off) { a = l1[t - off]; b = l2[t - off]; }
        __syncthreads();
        l1[t] += a; l2[t] += b;
        __syncthreads();
    }
    if (t < NB) {
        sum1[t] = l1[t] - v1;
        sum2[t] = l2[t] - v2;
    }
    if (t == NB - 1) { base[N] = l1[t]; pbase[N] = l2[t]; }
}

// ---------------------------------------------------------------------------
// Phase 3: intra-block exclusive scan + block offset -> base/pbase; zero cur.
// ---------------------------------------------------------------------------
__global__ __launch_bounds__(256) void scan3_kernel(
    const int* __restrict__ cnt, const int* __restrict__ sum1,
    const int* __restrict__ sum2, int* __restrict__ base,
    int* __restrict__ pbase, int* __restrict__ cur, int N) {
    __shared__ int l1[256], l2[256];
    const int t = threadIdx.x;
    const int i = blockIdx.x * 256 + t;
    const int c = (i < N) ? cnt[i] : 0;
    const int p = (c + 15) & ~15;
    l1[t] = c; l2[t] = p;
    __syncthreads();
    for (int off = 1; off < 256; off <<= 1) {
        int a = 0, b = 0;
        if (t >= off) { a = l1[t - off]; b = l2[t - off]; }
        __syncthreads();
        l1[t] += a; l2[t] += b;
        __syncthreads();
    }
    if (i < N) {
        base[i]  = sum1[blockIdx.x] + l1[t] - c;
        pbase[i] = sum2[blockIdx.x] + l2[t] - p;
        cur[i] = 0;
    }
}

// ---------------------------------------------------------------------------
// FUSED mid-stage kernel (round-22 proven): padfill ∥ scatter ∥ gemm ∥ wcc
// via blockIdx bands; disjoint write sets; overlaps latency-bound scatter
// with VALU-bound gemm across CUs.
// ---------------------------------------------------------------------------
__global__ __launch_bounds__(512, 4) void fused_mid_kernel(
    const unsigned* __restrict__ raw, const int* __restrict__ cnt,
    const int* __restrict__ pbase, int* __restrict__ cur,
    int2* __restrict__ epad,
    const float* __restrict__ A, const float* __restrict__ W,
    float* __restrict__ P,
    const float* __restrict__ Wc, const float* __restrict__ Wcat,
    float* __restrict__ wcc,
    int N, int E, int NPF, int NSC, int NG) {
    const int bid = blockIdx.x;
    if (bid < NPF) {
        const int v = bid * 512 + (int)threadIdx.x;
        if (v < N) {
            const int s = pbase[v] + cnt[v];
            const int t = pbase[v + 1];
            for (int p = s; p < t; ++p) epad[p] = make_int2(0, 0);
        }
        if (bid == 0 && threadIdx.x < 64) {
            const int tail = pbase[N];
            epad[tail + threadIdx.x] = make_int2(0, 0);
        }
        return;
    }
    if (bid < NPF + NSC) {
        __shared__ int s_is64;
        if (threadIdx.x == 0) {
            unsigned acc = 0;
            for (int i = 1; i < 512; i += 2) acc |= raw[i];
            s_is64 = (acc == 0) ? 1 : 0;
        }
        __syncthreads();
        const int is64 = s_is64;
        const int tid = (bid - NPF) * 512 + (int)threadIdx.x;
        const int stride = NSC * 512;
        if (is64) {
            for (int e = tid; e < E; e += stride) {
                const int c = (int)raw[(size_t)2 * e];
                const int n = (int)raw[(size_t)2 * E + (size_t)2 * e];
                const int pos = pbase[c] + atomicAdd(&cur[c], 1);
                epad[pos] = make_int2(e, n);
            }
        } else {
            for (int e = tid; e < E; e += stride) {
                const int c = (int)raw[e];
                const int n = (int)raw[(size_t)E + e];
                const int pos = pbase[c] + atomicAdd(&cur[c], 1);
                epad[pos] = make_int2(e, n);
            }
        }
        return;
    }
    if (bid < NPF + NSC + NG) {
        __shared__ float Ws[ND * ND];
        {
            float4* d = (float4*)Ws;
            const float4* s = (const float4*)W;
            for (int i = threadIdx.x; i < (ND * ND) / 4; i += 512) d[i] = s[i];
        }
        __syncthreads();
        const int bg = bid - NPF - NSC;
        const int slot = (int)(threadIdx.x >> 5);
        const int j0 = ((int)threadIdx.x & 31) * 4;
        const int rbase = bg * 64 + slot * 4;
        const int r0 = (rbase + 0 < N) ? rbase + 0 : N - 1;
        const int r1 = (rbase + 1 < N) ? rbase + 1 : N - 1;
        const int r2 = (rbase + 2 < N) ? rbase + 2 : N - 1;
        const int r3 = (rbase + 3 < N) ? rbase + 3 : N - 1;
        const float* ap0 = A + (size_t)r0 * ND;
        const float* ap1 = A + (size_t)r1 * ND;
        const float* ap2 = A + (size_t)r2 * ND;
        const float* ap3 = A + (size_t)r3 * ND;
        float4 acc0 = {0,0,0,0}, acc1 = {0,0,0,0};
        float4 acc2 = {0,0,0,0}, acc3 = {0,0,0,0};
#pragma unroll 2
        for (int c = 0; c < 32; ++c) {
            const float4 a0 = *(const float4*)(ap0 + c * 4);
            const float4 a1 = *(const float4*)(ap1 + c * 4);
            const float4 a2 = *(const float4*)(ap2 + c * 4);
            const float4 a3 = *(const float4*)(ap3 + c * 4);
#pragma unroll
            for (int kk = 0; kk < 4; ++kk) {
                const float4 w = *(const float4*)&Ws[(c * 4 + kk) * ND + j0];
                const float x0 = ((const float*)&a0)[kk];
                const float x1 = ((const float*)&a1)[kk];
                const float x2 = ((const float*)&a2)[kk];
                const float x3 = ((const float*)&a3)[kk];
                acc0.x += x0 * w.x; acc0.y += x0 * w.y;
                acc0.z += x0 * w.z; acc0.w += x0 * w.w;
                acc1.x += x1 * w.x; acc1.y += x1 * w.y;
                acc1.z += x1 * w.z; acc1.w += x1 * w.w;
                acc2.x += x2 * w.x; acc2.y += x2 * w.y;
                acc2.z += x2 * w.z; acc2.w += x2 * w.w;
                acc3.x += x3 * w.x; acc3.y += x3 * w.y;
                acc3.z += x3 * w.z; acc3.w += x3 * w.w;
            }
        }
        if (rbase + 0 < N) *(float4*)&P[(size_t)r0 * ND + j0] = acc0;
        if (rbase + 1 < N) *(float4*)&P[(size_t)r1 * ND + j0] = acc1;
        if (rbase + 2 < N) *(float4*)&P[(size_t)r2 * ND + j0] = acc2;
        if (rbase + 3 < N) *(float4*)&P[(size_t)r3 * ND + j0] = acc3;
        return;
    }
    {
        const int bw = bid - NPF - NSC - NG;
        const int i = bw * 4 + ((int)threadIdx.x >> 7);
        const int j = (int)threadIdx.x & 127;
        float acc = 0.f;
        for (int k = 0; k < ND; ++k)
            acc += Wc[i * ND + k] * Wcat[k * ND + j];
        wcc[i * ND + j] = acc;
    }
}

// ---------------------------------------------------------------------------
// MFMA segmented edge reduction (round-17/22 proven EXACT: 3-term split-bf16,
// B frags resident in registers at VGPR=112 / 4 waves-SIMD — both the
// LDS-B (r18) and low-VGPR/high-occupancy (r23) variants measured worse).
// ---------------------------------------------------------------------------
__global__ __launch_bounds__(256) void seg_mfma_kernel(
    const int* __restrict__ base, const int* __restrict__ pbase,
    const int2* __restrict__ epad, const float* __restrict__ edge_attr,
    const float* __restrict__ W_edge, const float* __restrict__ P,
    float* __restrict__ m, int N, int CPW) {
    const int l   = (int)threadIdx.x & 63;
    const int r16 = l & 15;
    const int kg  = l >> 4;
    bf16x8 bh[8], bl[8];
#pragma unroll
    for (int t = 0; t < 8; ++t) {
#pragma unroll
        for (int j = 0; j < 8; ++j) {
            const float wv = W_edge[(kg * 8 + j) * ND + t * 16 + r16];
            const unsigned short h = f32_to_bf16(wv);
            bh[t][j] = (short)h;
            bl[t][j] = (short)f32_to_bf16(wv - bf16f(h));
        }
    }
    const f32x4 zero = {0.f, 0.f, 0.f, 0.f};
    const int wid = blockIdx.x * 4 + ((int)threadIdx.x >> 6);
    const int v0 = wid * CPW;
    if (v0 >= N) return;
    const int v1 = min(v0 + CPW, N);

    int pos = pbase[v0];
    int2 epA = epad[pos + r16];
    int2 epB = epad[pos + 16 + r16];
    float4 xA, yA, xB, yB;
    {
        const float* ap = edge_attr + (size_t)epA.x * ED + kg * 8;
        xA = *(const float4*)ap; yA = *(const float4*)(ap + 4);
        const float* bp = edge_attr + (size_t)epB.x * ED + kg * 8;
        xB = *(const float4*)bp; yB = *(const float4*)(bp + 4);
    }

    for (int v = v0; v < v1; ++v) {
        const int vend = pbase[v] + (base[v + 1] - base[v]);
        const int pend = pbase[v + 1];
        float part[8] = {0.f, 0.f, 0.f, 0.f, 0.f, 0.f, 0.f, 0.f};
        while (pos < pend) {
            const int2 epC = epad[pos + 32 + r16];
            float4 x = xA, y = yA;
            if (pos + r16 >= vend) {
                x.x = x.y = x.z = x.w = 0.f;
                y = x;
            }
            bf16x8 ah, al;
#pragma unroll
            for (int j = 0; j < 4; ++j) {
                const float fx = ((const float*)&x)[j];
                const unsigned short hx = f32_to_bf16(fx);
                ah[j] = (short)hx;
                al[j] = (short)f32_to_bf16(fx - bf16f(hx));
                const float fy = ((const float*)&y)[j];
                const unsigned short hy = f32_to_bf16(fy);
                ah[4 + j] = (short)hy;
                al[4 + j] = (short)f32_to_bf16(fy - bf16f(hy));
            }
            const int n0 = __shfl(epA.y, kg * 4 + 0, 16);
            const int n1 = __shfl(epA.y, kg * 4 + 1, 16);
            const int n2 = __shfl(epA.y, kg * 4 + 2, 16);
            const int n3 = __shfl(epA.y, kg * 4 + 3, 16);
            const float* q0 = P + (size_t)n0 * ND + r16;
            const float* q1 = P + (size_t)n1 * ND + r16;
            const float* q2 = P + (size_t)n2 * ND + r16;
            const float* q3 = P + (size_t)n3 * ND + r16;
#pragma unroll
            for (int t = 0; t < 8; ++t) {
                f32x4 D = __builtin_amdgcn_mfma_f32_16x16x32_bf16(
                    ah, bh[t], zero, 0, 0, 0);
                D = __builtin_amdgcn_mfma_f32_16x16x32_bf16(
                    al, bh[t], D, 0, 0, 0);
                D = __builtin_amdgcn_mfma_f32_16x16x32_bf16(
                    ah, bl[t], D, 0, 0, 0);
                part[t] += D[0] * q0[t * 16];
                part[t] += D[1] * q1[t * 16];
                part[t] += D[2] * q2[t * 16];
                part[t] += D[3] * q3[t * 16];
            }
            epA = epB; xA = xB; yA = yB;
            epB = epC;
            const float* np = edge_attr + (size_t)epB.x * ED + kg * 8;
            xB = *(const float4*)np;
            yB = *(const float4*)(np + 4);
            pos += 16;
        }
#pragma unroll
        for (int t = 0; t < 8; ++t) {
            part[t] += __shfl_xor(part[t], 16);
            part[t] += __shfl_xor(part[t], 32);
        }
        if (l < 16) {
#pragma unroll
            for (int t = 0; t < 8; ++t)
                m[(size_t)v * ND + t * 16 + l] = part[t];
        }
    }
}

// ---------------------------------------------------------------------------
// Fused final: out[r] = LN(node_attr[r]@wcc + m[r]@W_bot). (proven)
// ---------------------------------------------------------------------------
__global__ __launch_bounds__(512, 4) void final_kernel(
    const float* __restrict__ A1, const float* __restrict__ A2,
    const float* __restrict__ W1, const float* __restrict__ W2,
    const float* __restrict__ lnw, const float* __restrict__ lnb,
    float* __restrict__ out, int N) {
    __shared__ float Ws[ND * ND];
    const int slot = (int)(threadIdx.x >> 5);
    const int j0 = ((int)threadIdx.x & 31) * 4;
    const int rbase = blockIdx.x * 64 + slot * 4;
    const int r0 = (rbase + 0 < N) ? rbase + 0 : N - 1;
    const int r1 = (rbase + 1 < N) ? rbase + 1 : N - 1;
    const int r2 = (rbase + 2 < N) ? rbase + 2 : N - 1;
    const int r3 = (rbase + 3 < N) ? rbase + 3 : N - 1;
    float4 acc0 = {0,0,0,0}, acc1 = {0,0,0,0};
    float4 acc2 = {0,0,0,0}, acc3 = {0,0,0,0};

#define K_PHASE(AP, WP)                                                       \
    {                                                                         \
        {                                                                     \
            float4* d = (float4*)Ws;                                          \
            const float4* sw = (const float4*)(WP);                           \
            for (int i = threadIdx.x; i < (ND * ND) / 4; i += 512)            \
                d[i] = sw[i];                                                 \
        }                                                                     \
        __syncthreads();                                                      \
        const float* ap0 = (AP) + (size_t)r0 * ND;                            \
        const float* ap1 = (AP) + (size_t)r1 * ND;                            \
        const float* ap2 = (AP) + (size_t)r2 * ND;                            \
        const float* ap3 = (AP) + (size_t)r3 * ND;                            \
        _Pragma("unroll 2")                                                   \
        for (int c = 0; c < 32; ++c) {                                        \
            const float4 a0 = *(const float4*)(ap0 + c * 4);                  \
            const float4 a1 = *(const float4*)(ap1 + c * 4);                  \
            const float4 a2 = *(const float4*)(ap2 + c * 4);                  \
            const float4 a3 = *(const float4*)(ap3 + c * 4);                  \
            _Pragma("unroll")                                                 \
            for (int kk = 0; kk < 4; ++kk) {                                  \
                const float4 w = *(const float4*)&Ws[(c * 4 + kk) * ND + j0]; \
                const float x0 = ((const float*)&a0)[kk];                     \
                const float x1 = ((const float*)&a1)[kk];                     \
                const float x2 = ((const float*)&a2)[kk];                     \
                const float x3 = ((const float*)&a3)[kk];                     \
                acc0.x += x0 * w.x; acc0.y += x0 * w.y;                       \
                acc0.z += x0 * w.z; acc0.w += x0 * w.w;                       \
                acc1.x += x1 * w.x; acc1.y += x1 * w.y;                       \
                acc1.z += x1 * w.z; acc1.w += x1 * w.w;                       \
                acc2.x += x2 * w.x; acc2.y += x2 * w.y;                       \
                acc2.z += x2 * w.z; acc2.w += x2 * w.w;                       \
                acc3.x += x3 * w.x; acc3.y += x3 * w.y;                       \
                acc3.z += x3 * w.z; acc3.w += x3 * w.w;                       \
            }                                                                 \
        }                                                                     \
        __syncthreads();                                                      \
    }

    K_PHASE(A1, W1)
    K_PHASE(A2, W2)
#undef K_PHASE

    const float4 w4 = *(const float4*)&lnw[j0];
    const float4 b4 = *(const float4*)&lnb[j0];
#define LN_ROW(ACC, RQ, VALID)                                               \
    {                                                                        \
        float4 h = ACC;                                                      \
        float sum = h.x + h.y + h.z + h.w;                                   \
        sum += __shfl_xor(sum, 16); sum += __shfl_xor(sum, 8);               \
        sum += __shfl_xor(sum, 4);  sum += __shfl_xor(sum, 2);               \
        sum += __shfl_xor(sum, 1);                                           \
        const float mean = sum * (1.f / ND);                                 \
        const float4 dd = {h.x - mean, h.y - mean, h.z - mean, h.w - mean};  \
        float qv = dd.x * dd.x + dd.y * dd.y + dd.z * dd.z + dd.w * dd.w;    \
        qv += __shfl_xor(qv, 16); qv += __shfl_xor(qv, 8);                   \
        qv += __shfl_xor(qv, 4);  qv += __shfl_xor(qv, 2);                   \
        qv += __shfl_xor(qv, 1);                                             \
        const float rstd = rsqrtf(qv * (1.f / ND) + LN_EPS);                 \
        if (VALID) {                                                         \
            float4 o;                                                        \
            o.x = dd.x * rstd * w4.x + b4.x;                                 \
            o.y = dd.y * rstd * w4.y + b4.y;                                 \
            o.z = dd.z * rstd * w4.z + b4.z;                                 \
            o.w = dd.w * rstd * w4.w + b4.w;                                 \
            *(float4*)&out[(size_t)(RQ) * ND + j0] = o;                      \
        }                                                                    \
    }
    LN_ROW(acc0, r0, rbase + 0 < N)
    LN_ROW(acc1, r1, rbase + 1 < N)
    LN_ROW(acc2, r2, rbase + 2 < N)
    LN_ROW(acc3, r3, rbase + 3 < N)
#undef LN_ROW
}

// ---------------------------------------------------------------------------
extern "C" void kernel_launch(void* const* d_in, const int* in_sizes, int n_in,
                              void* d_out, int out_size, void* d_ws, size_t ws_size,
                              hipStream_t stream) {
    const float*    node_attr = (const float*)d_in[0];
    const float*    edge_attr = (const float*)d_in[1];
    const unsigned* edge_idx  = (const unsigned*)d_in[2];
    const float*    W_node    = (const float*)d_in[3];
    const float*    W_center  = (const float*)d_in[4];
    const float*    W_concat  = (const float*)d_in[5];
    const float*    W_edge    = (const float*)d_in[6];
    const float*    lnw       = (const float*)d_in[7];
    const float*    lnb       = (const float*)d_in[8];
    float* out = (float*)d_out;

    const int N = in_sizes[0] / ND;   // 50000
    const int E = in_sizes[1] / ED;   // 800000
    const int NB = (N + 255) / 256;
    const size_t PADCAP = (size_t)E + 15 * (size_t)N + 64;

    char* ws = (char*)d_ws;
    float* wcc   = (float*)ws;                          // 64 KB
    float* P     = (float*)(ws + 65536);                // [N,128]
    float* m     = P + (size_t)N * ND;                  // [N,128]
    int2*  epad  = (int2*)(m + (size_t)N * ND);         // [PADCAP]
    int*   cnt   = (int*)(epad + PADCAP);               // [N]
    int*   base  = cnt + N;                             // [N+1]
    int*   pbase = base + N + 1;                        // [N+1]
    int*   cur   = pbase + N + 1;                       // [N]
    int*   sum1  = cur + N;                             // [NB]
    int*   sum2  = sum1 + NB;                           // [NB]

    hipMemsetAsync(cnt, 0, (size_t)N * sizeof(int), stream);
    conv_hist_kernel<<<512, 256, 0, stream>>>(edge_idx, cnt, E);
    scan1_kernel<<<NB, 256, 0, stream>>>(cnt, sum1, sum2, N);
    scan2_kernel<<<1, 1024, 0, stream>>>(sum1, sum2, base, pbase, NB, N);
    scan3_kernel<<<NB, 256, 0, stream>>>(cnt, sum1, sum2, base, pbase, cur, N);
    {
        const int NPF = (N + 511) / 512;     // padfill blocks
        const int NSC = 256;                 // scatter blocks
        const int NG  = (N + 63) / 64;       // gemm blocks
        const int NW  = 32;                  // wcc blocks
        fused_mid_kernel<<<NPF + NSC + NG + NW, 512, 0, stream>>>(
            edge_idx, cnt, pbase, cur, epad,
            node_attr, W_node, P,
            W_center, W_concat, wcc,
            N, E, NPF, NSC, NG);
    }
    {
        const int nwaves = 1024 * 4;                 // round-17/22 proven
        const int cpw = (N + nwaves - 1) / nwaves;   // 13 for N=50000
        seg_mfma_kernel<<<1024, 256, 0, stream>>>(base, pbase, epad,
                                                  edge_attr, W_edge, P, m,
                                                  N, cpw);
    }
    final_kernel<<<(N + 63) / 64, 512, 0, stream>>>(node_attr, m, wcc,
                                                    W_concat + ND * ND,
                                                    lnw, lnb, out, N);
}